// Round 4
// baseline (357.273 us; speedup 1.0000x reference)
//
#include <hip/hip_runtime.h>
#include <math.h>

// N=64, C=256, T=64, V=25 graph-ODE, 4 fused blocks. bf16 MFMA 32x32x16.
// R4: S=1 slab/WG + manual LDS layout.
// R5: Phase-G software pipeline (depth-4 rotating w regs).
// R6: FAILED - resv[32] register residual spilled to scratch.
// R7: barrier reposition + setprio: neutral. Structure-bound.
// R8: syT ELIMINATED. Each wave computes full y in-register (8 c-tiles,
//     4x redundant MFMA) and converts Phase-A accumulators directly into
//     Phase-G B-frags via v_permlane32_swap_b32 (T12 mechanism). No y LDS
//     round-trip, no pack/ds_write, LDS 40.3->26.6 KB; 2 barriers/block
//     now fence only sres (all-rows read vs epilogue write).
#define NN 64
#define CC 256
#define TT 64
#define VV 25

typedef __bf16 bf16;
typedef __attribute__((ext_vector_type(8)))  __bf16 bf16x8;
typedef __attribute__((ext_vector_type(16))) float  f32x16;
typedef __attribute__((ext_vector_type(4)))  unsigned int uint4v;

#define RS 40    // sres row stride (bf16): 80 B

// Manual LDS layout (bytes).
#define OFF_SRES  0        // 256*40*2 = 20480
#define OFF_SAB   20480    // 32*32*2  = 2048
#define OFF_SBIAS 22528    // 4*256*4  = 4096
#define SMEM_BYTES 26624   // -> LDS allows 6 WGs/CU; VGPR (<=128) gives 4

// ---- pack the four 256x256 fp32 w into bf16 MFMA A-fragment order ----
// wp[((blk*4+wv)*16+k)*1024 + pair*512 + lane*8 + e]
//   = w_blk[wv*64+pair*32+(lane&31)][k*16+(lane>>5)*8+e]
__global__ void convert_w(const float* __restrict__ w1, const float* __restrict__ w2,
                          const float* __restrict__ w3, const float* __restrict__ w4,
                          bf16* __restrict__ wp) {
    const int gid = blockIdx.x * 256 + threadIdx.x;   // 0..32767
    const int e8  = gid * 8;                          // linear over 4*65536 elems
    const int blk = e8 >> 16;
    const int off = e8 & 65535;
    const int row = off >> 8;
    const int col = off & 255;
    const float* src = (blk == 0) ? w1 : (blk == 1) ? w2 : (blk == 2) ? w3 : w4;
    const float4 f0 = *(const float4*)(src + off);        // coalesced reads
    const float4 f1 = *(const float4*)(src + off + 4);
    bf16x8 o;
    o[0] = (bf16)f0.x; o[1] = (bf16)f0.y; o[2] = (bf16)f0.z; o[3] = (bf16)f0.w;
    o[4] = (bf16)f1.x; o[5] = (bf16)f1.y; o[6] = (bf16)f1.z; o[7] = (bf16)f1.w;
    const int wv = row >> 6, pair = (row >> 5) & 1, l31 = row & 31;
    const int k = col >> 4, lh = (col >> 3) & 1;
    wp += (((size_t)(blk * 4 + wv) * 16 + k) * 1024) + pair * 512 + (lh * 32 + l31) * 8;
    *(bf16x8*)wp = o;
}

#define MFMA(A, B, C) __builtin_amdgcn_mfma_f32_32x32x16_bf16(A, B, C, 0, 0, 0)

// pack two f32 -> one dword of 2 bf16 (lo, hi)
static __device__ __forceinline__ unsigned int pkbf(float a, float b) {
    unsigned short lo = __builtin_bit_cast(unsigned short, (__bf16)a);
    unsigned short hi = __builtin_bit_cast(unsigned short, (__bf16)b);
    return (unsigned int)lo | ((unsigned int)hi << 16);
}

__global__ __launch_bounds__(256, 4) void ode_mfma(
    const float* __restrict__ x, const float* __restrict__ Amat,
    const bf16* __restrict__ wp,
    const float* __restrict__ b1, const float* __restrict__ b2,
    const float* __restrict__ b3, const float* __restrict__ b4,
    float* __restrict__ out)
{
    __shared__ __attribute__((aligned(16))) char smem[SMEM_BYTES];
    bf16*  sres  = (bf16*)(smem + OFF_SRES);    // [c][RS]
    bf16*  sAb   = (bf16*)(smem + OFF_SAB);     // [v][32]
    float* sbias = (float*)(smem + OFF_SBIAS);  // [4][CC]

    const int t    = blockIdx.x;
    const int n    = blockIdx.y;
    const int tid  = threadIdx.x;
    const int wave = tid >> 6;
    const int lane = tid & 63;
    const int lh   = lane >> 5;
    const int l31  = lane & 31;
    const int o0   = wave * 64;

    // ---- blk0 w-prefetch: no LDS dependency; latency hides under staging ----
    bf16x8 wA[4], wB[4];
    {
        const bf16* wb0 = wp + ((size_t)wave * 16) * 1024 + lane * 8;
        #pragma unroll
        for (int q = 0; q < 4; ++q) {
            wA[q] = *(const bf16x8*)(wb0 + q * 1024);
            wB[q] = *(const bf16x8*)(wb0 + q * 1024 + 512);
        }
    }

    // ---- stage biases (coalesced) ----
    sbias[0 * CC + tid] = b1[tid];
    sbias[1 * CC + tid] = b2[tid];
    sbias[2 * CC + tid] = b3[tid];
    sbias[3 * CC + tid] = b4[tid];

    // ---- stage A, zero-padded to 32x32 ----
    for (int i = tid; i < 32 * 32; i += 256) {
        const int v = i >> 5, u = i & 31;
        sAb[i] = (v < VV && u < VV) ? (bf16)Amat[v * VV + u] : (bf16)0.f;
    }

    // ---- stage x slab ----
    {
        const float* xb = x + ((size_t)n * CC * TT + t) * VV;  // + c*T*V + v
        for (int i = tid; i < CC * VV; i += 256) {
            const int c = i / VV;
            const int v = i - c * VV;
            sres[c * RS + v] = (bf16)xb[(size_t)c * TT * VV + v];
        }
        #pragma unroll
        for (int u = VV; u < 32; ++u) sres[tid * RS + u] = (bf16)0.f;  // tid == c
    }
    __syncthreads();

    // A-matrix B-fragments: constant across blocks (rows >= VV are zero-padded).
    const bf16x8 bfA0 = *(const bf16x8*)&sAb[l31 * 32 + lh * 8];
    const bf16x8 bfA1 = *(const bf16x8*)&sAb[l31 * 32 + 16 + lh * 8];

    for (int blk = 0; blk < 4; ++blk) {
        const bf16* wbase = wp + ((size_t)(blk * 4 + wave) * 16) * 1024 + lane * 8;
        f32x16 acc0 = {}, acc1 = {};

        // af double-buffer: ds_read for c-tile ct+1 issued during ct's compute.
        bf16x8 afA[2], afB[2];
        afA[0] = *(const bf16x8*)&sres[l31 * RS + lh * 8];
        afB[0] = *(const bf16x8*)&sres[l31 * RS + 16 + lh * 8];

        #pragma unroll
        for (int ct = 0; ct < 8; ++ct) {
            const int cur = ct & 1;
            if (ct < 7) {
                afA[cur ^ 1] = *(const bf16x8*)&sres[((ct + 1) * 32 + l31) * RS + lh * 8];
                afB[cur ^ 1] = *(const bf16x8*)&sres[((ct + 1) * 32 + l31) * RS + 16 + lh * 8];
            }
            // ---- Phase A for c-tile ct, in-register (redundant across waves) ----
            // dA: col v = l31, row c~ = (q&3) + 8*(q>>2) + 4*lh
            f32x16 dA = {};
            dA = MFMA(afA[cur], bfA0, dA);
            dA = MFMA(afB[cur], bfA1, dA);

            // pack rows into dwords: wj = (d[2j], d[2j+1])
            unsigned int w0 = pkbf(dA[0],  dA[1]),  w1 = pkbf(dA[2],  dA[3]);
            unsigned int w2 = pkbf(dA[4],  dA[5]),  w3 = pkbf(dA[6],  dA[7]);
            unsigned int w4 = pkbf(dA[8],  dA[9]),  w5 = pkbf(dA[10], dA[11]);
            unsigned int w6 = pkbf(dA[12], dA[13]), w7 = pkbf(dA[14], dA[15]);
            // lh-half fixup: swap(a,b): a.hi-lanes <- b.lo-lanes, b.lo <- a.hi.
            // After swap, {w0,w1,w2,w3} is exactly the ks=0 B-frag (col v=l31,
            // kappa=lh*8+e over c~=0..15), {w4..w7} the ks=1 frag (c~=16..31).
            asm("v_permlane32_swap_b32 %0, %1" : "+v"(w0), "+v"(w2));
            asm("v_permlane32_swap_b32 %0, %1" : "+v"(w1), "+v"(w3));
            asm("v_permlane32_swap_b32 %0, %1" : "+v"(w4), "+v"(w6));
            asm("v_permlane32_swap_b32 %0, %1" : "+v"(w5), "+v"(w7));
            const bf16x8 y0 = __builtin_bit_cast(bf16x8, (uint4v){w0, w1, w2, w3});
            const bf16x8 y1 = __builtin_bit_cast(bf16x8, (uint4v){w4, w5, w6, w7});

            // ---- Phase G k-steps k0=2ct, k1=2ct+1; w rotated depth-4 ----
            const int k0 = 2 * ct, k1 = 2 * ct + 1;
            acc0 = MFMA(wA[k0 & 3], y0, acc0);
            acc1 = MFMA(wB[k0 & 3], y0, acc1);
            if (k0 + 4 < 16) {
                wA[k0 & 3] = *(const bf16x8*)(wbase + (k0 + 4) * 1024);
                wB[k0 & 3] = *(const bf16x8*)(wbase + (k0 + 4) * 1024 + 512);
            }
            acc0 = MFMA(wA[k1 & 3], y1, acc0);
            acc1 = MFMA(wB[k1 & 3], y1, acc1);
            if (k1 + 4 < 16) {
                wA[k1 & 3] = *(const bf16x8*)(wbase + (k1 + 4) * 1024);
                wB[k1 & 3] = *(const bf16x8*)(wbase + (k1 + 4) * 1024 + 512);
            }
        }
        __syncthreads();   // barrier1: ALL waves' sres reads done (reads span
                           // all 256 rows) before any epilogue write.

        // ---- prefetch next block's w: hides under the epilogue ----
        if (blk < 3) {
            const bf16* wn = wp + ((size_t)((blk + 1) * 4 + wave) * 16) * 1024 + lane * 8;
            #pragma unroll
            for (int q = 0; q < 4; ++q) {
                wA[q] = *(const bf16x8*)(wn + q * 1024);
                wB[q] = *(const bf16x8*)(wn + q * 1024 + 512);
            }
        }

        // ===== Epilogue: out[o][v] = relu(acc + b[o] + res[o][v]) =====
        const int v = l31;
        #define EPILOGUE(ACC, OT)                                                   \
            _Pragma("unroll")                                                       \
            for (int g = 0; g < 4; ++g) {                                           \
                const int ob = o0 + (OT) * 32 + 8 * g + 4 * lh;                     \
                const float4 bq = *(const float4*)&sbias[blk * CC + ob];            \
                _Pragma("unroll")                                                   \
                for (int r = 0; r < 4; ++r) {                                       \
                    const int o = ob + r;                                           \
                    float val = ACC[4 * g + r] + ((const float*)&bq)[r]             \
                              + (float)sres[o * RS + v];                            \
                    val = fmaxf(val, 0.f);                                          \
                    if (v < VV) {                                                   \
                        if (blk < 3) sres[o * RS + v] = (bf16)val;                  \
                        else out[(((size_t)n * CC + o) * TT + t) * VV + v] = val;   \
                    }                                                               \
                }                                                                   \
            }
        EPILOGUE(acc0, 0)
        EPILOGUE(acc1, 1)
        #undef EPILOGUE
        __syncthreads();   // barrier2: epilogue sres writes -> next block reads
    }
}

extern "C" void kernel_launch(void* const* d_in, const int* in_sizes, int n_in,
                              void* d_out, int out_size, void* d_ws, size_t ws_size,
                              hipStream_t stream) {
    const float* x  = (const float*)d_in[1];
    const float* A  = (const float*)d_in[2];
    const float* w1 = (const float*)d_in[3];
    const float* b1 = (const float*)d_in[4];
    const float* w2 = (const float*)d_in[5];
    const float* b2 = (const float*)d_in[6];
    const float* w3 = (const float*)d_in[7];
    const float* b3 = (const float*)d_in[8];
    const float* w4 = (const float*)d_in[9];
    const float* b4 = (const float*)d_in[10];
    float* out = (float*)d_out;
    bf16* wp = (bf16*)d_ws;   // 512 KB packed w fragments

    convert_w<<<128, 256, 0, stream>>>(w1, w2, w3, w4, wp);
    dim3 grid(TT, NN);        // one WG per (n,t) slab: 4096 WGs
    ode_mfma<<<grid, 256, 0, stream>>>(x, A, wp, b1, b2, b3, b4, out);
}

// Round 6
// 349.600 us; speedup vs baseline: 1.0219x; 1.0219x over previous
//
#include <hip/hip_runtime.h>
#include <math.h>

// N=64, C=256, T=64, V=25 graph-ODE, 4 fused blocks. bf16 MFMA 32x32x16.
// R4: S=1 slab/WG + manual LDS layout.
// R5: Phase-G software pipeline (depth-4 rotating w regs).
// R6: FAILED - resv[32] register residual spilled to scratch.
// R7: barrier reposition + setprio: neutral. Structure-bound.
// R8: syT eliminated via in-register y (permlane32_swap). LDS 40.3->26.6 KB,
//     but VALU-heavier and stuck at 4 WGs/CU: 199us.
// R9: FAILED - __launch_bounds__(256,6) forced VGPR cap 84 -> miscompile
//     (absmax 2.6). Never force a tighter reg budget than the proven build.
// R10: same R8 body, __launch_bounds__(256) with NO min-waves: allocator
//      unconstrained (correct codegen path), hardware residency resource-
//      driven -> 6 WGs/CU by LDS if natural VGPR <= 85. Clean A/B on
//      whether the min-waves attr was pinning residency at 4 WGs.
#define NN 64
#define CC 256
#define TT 64
#define VV 25

typedef __bf16 bf16;
typedef __attribute__((ext_vector_type(8)))  __bf16 bf16x8;
typedef __attribute__((ext_vector_type(16))) float  f32x16;
typedef __attribute__((ext_vector_type(4)))  unsigned int uint4v;

#define RS 40    // sres row stride (bf16): 80 B

// Manual LDS layout (bytes).
#define OFF_SRES  0        // 256*40*2 = 20480
#define OFF_SAB   20480    // 32*32*2  = 2048
#define OFF_SBIAS 22528    // 4*256*4  = 4096
#define SMEM_BYTES 26624   // 6 WGs/CU: 6*26624 = 159744 <= 163840

// ---- pack the four 256x256 fp32 w into bf16 MFMA A-fragment order ----
// wp[((blk*4+wv)*16+k)*1024 + pair*512 + lane*8 + e]
//   = w_blk[wv*64+pair*32+(lane&31)][k*16+(lane>>5)*8+e]
__global__ void convert_w(const float* __restrict__ w1, const float* __restrict__ w2,
                          const float* __restrict__ w3, const float* __restrict__ w4,
                          bf16* __restrict__ wp) {
    const int gid = blockIdx.x * 256 + threadIdx.x;   // 0..32767
    const int e8  = gid * 8;                          // linear over 4*65536 elems
    const int blk = e8 >> 16;
    const int off = e8 & 65535;
    const int row = off >> 8;
    const int col = off & 255;
    const float* src = (blk == 0) ? w1 : (blk == 1) ? w2 : (blk == 2) ? w3 : w4;
    const float4 f0 = *(const float4*)(src + off);        // coalesced reads
    const float4 f1 = *(const float4*)(src + off + 4);
    bf16x8 o;
    o[0] = (bf16)f0.x; o[1] = (bf16)f0.y; o[2] = (bf16)f0.z; o[3] = (bf16)f0.w;
    o[4] = (bf16)f1.x; o[5] = (bf16)f1.y; o[6] = (bf16)f1.z; o[7] = (bf16)f1.w;
    const int wv = row >> 6, pair = (row >> 5) & 1, l31 = row & 31;
    const int k = col >> 4, lh = (col >> 3) & 1;
    wp += (((size_t)(blk * 4 + wv) * 16 + k) * 1024) + pair * 512 + (lh * 32 + l31) * 8;
    *(bf16x8*)wp = o;
}

#define MFMA(A, B, C) __builtin_amdgcn_mfma_f32_32x32x16_bf16(A, B, C, 0, 0, 0)

// pack two f32 -> one dword of 2 bf16 (lo, hi)
static __device__ __forceinline__ unsigned int pkbf(float a, float b) {
    unsigned short lo = __builtin_bit_cast(unsigned short, (__bf16)a);
    unsigned short hi = __builtin_bit_cast(unsigned short, (__bf16)b);
    return (unsigned int)lo | ((unsigned int)hi << 16);
}

__global__ __launch_bounds__(256) void ode_mfma(
    const float* __restrict__ x, const float* __restrict__ Amat,
    const bf16* __restrict__ wp,
    const float* __restrict__ b1, const float* __restrict__ b2,
    const float* __restrict__ b3, const float* __restrict__ b4,
    float* __restrict__ out)
{
    __shared__ __attribute__((aligned(16))) char smem[SMEM_BYTES];
    bf16*  sres  = (bf16*)(smem + OFF_SRES);    // [c][RS]
    bf16*  sAb   = (bf16*)(smem + OFF_SAB);     // [v][32]
    float* sbias = (float*)(smem + OFF_SBIAS);  // [4][CC]

    const int t    = blockIdx.x;
    const int n    = blockIdx.y;
    const int tid  = threadIdx.x;
    const int wave = tid >> 6;
    const int lane = tid & 63;
    const int lh   = lane >> 5;
    const int l31  = lane & 31;
    const int o0   = wave * 64;

    // ---- blk0 w-prefetch: no LDS dependency; latency hides under staging ----
    bf16x8 wA[4], wB[4];
    {
        const bf16* wb0 = wp + ((size_t)wave * 16) * 1024 + lane * 8;
        #pragma unroll
        for (int q = 0; q < 4; ++q) {
            wA[q] = *(const bf16x8*)(wb0 + q * 1024);
            wB[q] = *(const bf16x8*)(wb0 + q * 1024 + 512);
        }
    }

    // ---- stage biases (coalesced) ----
    sbias[0 * CC + tid] = b1[tid];
    sbias[1 * CC + tid] = b2[tid];
    sbias[2 * CC + tid] = b3[tid];
    sbias[3 * CC + tid] = b4[tid];

    // ---- stage A, zero-padded to 32x32 ----
    for (int i = tid; i < 32 * 32; i += 256) {
        const int v = i >> 5, u = i & 31;
        sAb[i] = (v < VV && u < VV) ? (bf16)Amat[v * VV + u] : (bf16)0.f;
    }

    // ---- stage x slab ----
    {
        const float* xb = x + ((size_t)n * CC * TT + t) * VV;  // + c*T*V + v
        for (int i = tid; i < CC * VV; i += 256) {
            const int c = i / VV;
            const int v = i - c * VV;
            sres[c * RS + v] = (bf16)xb[(size_t)c * TT * VV + v];
        }
        #pragma unroll
        for (int u = VV; u < 32; ++u) sres[tid * RS + u] = (bf16)0.f;  // tid == c
    }
    __syncthreads();

    // A-matrix B-fragments: constant across blocks (rows >= VV are zero-padded).
    const bf16x8 bfA0 = *(const bf16x8*)&sAb[l31 * 32 + lh * 8];
    const bf16x8 bfA1 = *(const bf16x8*)&sAb[l31 * 32 + 16 + lh * 8];

    for (int blk = 0; blk < 4; ++blk) {
        const bf16* wbase = wp + ((size_t)(blk * 4 + wave) * 16) * 1024 + lane * 8;
        f32x16 acc0 = {}, acc1 = {};

        // af double-buffer: ds_read for c-tile ct+1 issued during ct's compute.
        bf16x8 afA[2], afB[2];
        afA[0] = *(const bf16x8*)&sres[l31 * RS + lh * 8];
        afB[0] = *(const bf16x8*)&sres[l31 * RS + 16 + lh * 8];

        #pragma unroll
        for (int ct = 0; ct < 8; ++ct) {
            const int cur = ct & 1;
            if (ct < 7) {
                afA[cur ^ 1] = *(const bf16x8*)&sres[((ct + 1) * 32 + l31) * RS + lh * 8];
                afB[cur ^ 1] = *(const bf16x8*)&sres[((ct + 1) * 32 + l31) * RS + 16 + lh * 8];
            }
            // ---- Phase A for c-tile ct, in-register (redundant across waves) ----
            // dA: col v = l31, row c~ = (q&3) + 8*(q>>2) + 4*lh
            f32x16 dA = {};
            dA = MFMA(afA[cur], bfA0, dA);
            dA = MFMA(afB[cur], bfA1, dA);

            // pack rows into dwords: wj = (d[2j], d[2j+1])
            unsigned int w0 = pkbf(dA[0],  dA[1]),  w1 = pkbf(dA[2],  dA[3]);
            unsigned int w2 = pkbf(dA[4],  dA[5]),  w3 = pkbf(dA[6],  dA[7]);
            unsigned int w4 = pkbf(dA[8],  dA[9]),  w5 = pkbf(dA[10], dA[11]);
            unsigned int w6 = pkbf(dA[12], dA[13]), w7 = pkbf(dA[14], dA[15]);
            // lh-half fixup: swap(a,b): a.hi-lanes <- b.lo-lanes, b.lo <- a.hi.
            // After swap, {w0,w1,w2,w3} is exactly the ks=0 B-frag (col v=l31,
            // kappa=lh*8+e over c~=0..15), {w4..w7} the ks=1 frag (c~=16..31).
            asm("v_permlane32_swap_b32 %0, %1" : "+v"(w0), "+v"(w2));
            asm("v_permlane32_swap_b32 %0, %1" : "+v"(w1), "+v"(w3));
            asm("v_permlane32_swap_b32 %0, %1" : "+v"(w4), "+v"(w6));
            asm("v_permlane32_swap_b32 %0, %1" : "+v"(w5), "+v"(w7));
            const bf16x8 y0 = __builtin_bit_cast(bf16x8, (uint4v){w0, w1, w2, w3});
            const bf16x8 y1 = __builtin_bit_cast(bf16x8, (uint4v){w4, w5, w6, w7});

            // ---- Phase G k-steps k0=2ct, k1=2ct+1; w rotated depth-4 ----
            const int k0 = 2 * ct, k1 = 2 * ct + 1;
            acc0 = MFMA(wA[k0 & 3], y0, acc0);
            acc1 = MFMA(wB[k0 & 3], y0, acc1);
            if (k0 + 4 < 16) {
                wA[k0 & 3] = *(const bf16x8*)(wbase + (k0 + 4) * 1024);
                wB[k0 & 3] = *(const bf16x8*)(wbase + (k0 + 4) * 1024 + 512);
            }
            acc0 = MFMA(wA[k1 & 3], y1, acc0);
            acc1 = MFMA(wB[k1 & 3], y1, acc1);
            if (k1 + 4 < 16) {
                wA[k1 & 3] = *(const bf16x8*)(wbase + (k1 + 4) * 1024);
                wB[k1 & 3] = *(const bf16x8*)(wbase + (k1 + 4) * 1024 + 512);
            }
        }
        __syncthreads();   // barrier1: ALL waves' sres reads done (reads span
                           // all 256 rows) before any epilogue write.

        // ---- prefetch next block's w: hides under the epilogue ----
        if (blk < 3) {
            const bf16* wn = wp + ((size_t)((blk + 1) * 4 + wave) * 16) * 1024 + lane * 8;
            #pragma unroll
            for (int q = 0; q < 4; ++q) {
                wA[q] = *(const bf16x8*)(wn + q * 1024);
                wB[q] = *(const bf16x8*)(wn + q * 1024 + 512);
            }
        }

        // ===== Epilogue: out[o][v] = relu(acc + b[o] + res[o][v]) =====
        const int v = l31;
        #define EPILOGUE(ACC, OT)                                                   \
            _Pragma("unroll")                                                       \
            for (int g = 0; g < 4; ++g) {                                           \
                const int ob = o0 + (OT) * 32 + 8 * g + 4 * lh;                     \
                const float4 bq = *(const float4*)&sbias[blk * CC + ob];            \
                _Pragma("unroll")                                                   \
                for (int r = 0; r < 4; ++r) {                                       \
                    const int o = ob + r;                                           \
                    float val = ACC[4 * g + r] + ((const float*)&bq)[r]             \
                              + (float)sres[o * RS + v];                            \
                    val = fmaxf(val, 0.f);                                          \
                    if (v < VV) {                                                   \
                        if (blk < 3) sres[o * RS + v] = (bf16)val;                  \
                        else out[(((size_t)n * CC + o) * TT + t) * VV + v] = val;   \
                    }                                                               \
                }                                                                   \
            }
        EPILOGUE(acc0, 0)
        EPILOGUE(acc1, 1)
        #undef EPILOGUE
        __syncthreads();   // barrier2: epilogue sres writes -> next block reads
    }
}

extern "C" void kernel_launch(void* const* d_in, const int* in_sizes, int n_in,
                              void* d_out, int out_size, void* d_ws, size_t ws_size,
                              hipStream_t stream) {
    const float* x  = (const float*)d_in[1];
    const float* A  = (const float*)d_in[2];
    const float* w1 = (const float*)d_in[3];
    const float* b1 = (const float*)d_in[4];
    const float* w2 = (const float*)d_in[5];
    const float* b2 = (const float*)d_in[6];
    const float* w3 = (const float*)d_in[7];
    const float* b3 = (const float*)d_in[8];
    const float* w4 = (const float*)d_in[9];
    const float* b4 = (const float*)d_in[10];
    float* out = (float*)d_out;
    bf16* wp = (bf16*)d_ws;   // 512 KB packed w fragments

    convert_w<<<128, 256, 0, stream>>>(w1, w2, w3, w4, wp);
    dim3 grid(TT, NN);        // one WG per (n,t) slab: 4096 WGs
    ode_mfma<<<grid, 256, 0, stream>>>(x, A, wp, b1, b2, b3, b4, out);
}